// Round 9
// baseline (630.176 us; speedup 1.0000x reference)
//
#include <hip/hip_runtime.h>
#include <hip/hip_bf16.h>
#include <stdint.h>

#define B_  4
#define T_  8192
#define H_  1024
#define NH_ 16
#define D_  64
#define BT_ (B_*T_)

typedef __attribute__((ext_vector_type(8))) __bf16 bf16x8;
typedef __attribute__((ext_vector_type(4))) __bf16 bf16x4;
typedef __attribute__((ext_vector_type(4))) float  f32x4;

__device__ __forceinline__ float phi_f(float x) {
    return x > 0.0f ? x + 1.0f : __expf(x);
}

__device__ __forceinline__ void async_copy16(const void* g, void* l) {
    __builtin_amdgcn_global_load_lds(
        (const __attribute__((address_space(1))) uint32_t*)g,
        (__attribute__((address_space(3))) uint32_t*)l, 16, 0, 0);
}

__global__ void wconv4(const float* __restrict__ s0, const float* __restrict__ s1,
                       const float* __restrict__ s2, const float* __restrict__ s3,
                       __bf16* __restrict__ d0, __bf16* __restrict__ d1,
                       __bf16* __restrict__ d2, __bf16* __restrict__ d3) {
    const float* s; __bf16* d;
    switch (blockIdx.y) {
        case 0: s = s0; d = d0; break;
        case 1: s = s1; d = d1; break;
        case 2: s = s2; d = d2; break;
        default: s = s3; d = d3; break;
    }
    int i = (blockIdx.x * 256 + threadIdx.x) * 4;
    float4 v = *(const float4*)(s + i);
    bf16x4 o;
    o[0] = (__bf16)v.x; o[1] = (__bf16)v.y; o[2] = (__bf16)v.z; o[3] = (__bf16)v.w;
    *(bf16x4*)(d + i) = o;
}

// ---------------------------------------------------------------------------
// Projection GEMM with FUSED fp32->bf16 A conversion:
// Out = epi( A_f32 @ W^T ), A register-staged (8xfloat4 -> cvt -> ds_write_b128
// into padded 144B-row LDS; 2-way bank aliasing = free), W bf16 via
// global_load_lds (pre-swizzled source -> XOR-swizzled conflict-free reads).
// XCD-bijective 1D swizzle keeps each XCD's fp32 A-panels L2-resident
// (round-1 post-mortem: without it, A re-fetch made this kernel BW-bound).
// EPI: 0 = Q' = z*phi -> bf16 (aux = Ksum), 1 = phi*mask -> bf16 (K),
//      2 = mask -> bf16 (V)
// ---------------------------------------------------------------------------
template<int EPI>
__global__ __launch_bounds__(256, 2)
void gemm_f32a(const float* __restrict__ A, const __bf16* __restrict__ Wb,
               const float* __restrict__ mask, const float* __restrict__ aux,
               __bf16* __restrict__ Out)
{
    const int orig = blockIdx.x;
    const int wgid = (orig & 7) * 256 + (orig >> 3);   // nwg=2048, bijective
    const int bm = (wgid >> 3) * 128;
    const int bn = (wgid & 7) * 128;
    const int tid  = threadIdx.x;
    const int lane = tid & 63;
    const int wid  = tid >> 6;
    const int wm = wid >> 1, wn = wid & 1;

    __shared__ __bf16 Al[128 * 72];   // padded rows: 144 B stride
    __shared__ __bf16 Bl[128 * 64];   // XOR-swizzled content

    f32x4 acc[4][4];
    #pragma unroll
    for (int i = 0; i < 4; ++i)
        #pragma unroll
        for (int j = 0; j < 4; ++j) acc[i][j] = (f32x4)0.0f;

    // A staging: thread covers row ar, 32-col half ah
    const int ar = tid >> 1;
    const int ah = (tid & 1) * 32;
    const float* aptr = A + (size_t)(bm + ar) * H_ + ah;
    char* alw = (char*)Al + ar * 144 + ah * 2;

    // B staging
    const int sn = wid * 8 + (lane >> 3);
    const int sc = (lane & 7) * 16;

    for (int k0 = 0; k0 < H_; k0 += 64) {
        // issue B async first (latency)
        #pragma unroll
        for (int issue = 0; issue < 4; ++issue) {
            int n = issue * 32 + sn;
            int csw = sc ^ ((n & 7) << 4);
            async_copy16((const char*)(Wb + (size_t)(bn + n) * H_ + k0) + csw,
                         (char*)Bl + issue * 4096 + wid * 1024);
        }
        // A: 8 x float4 -> 32 bf16 -> 4 x ds_write_b128
        {
            const float* ap = aptr + k0;
            float4 av[8];
            #pragma unroll
            for (int i = 0; i < 8; ++i) av[i] = ((const float4*)ap)[i];
            #pragma unroll
            for (int j = 0; j < 4; ++j) {
                float4 x = av[2*j], y = av[2*j+1];
                bf16x8 t;
                t[0]=(__bf16)x.x; t[1]=(__bf16)x.y; t[2]=(__bf16)x.z; t[3]=(__bf16)x.w;
                t[4]=(__bf16)y.x; t[5]=(__bf16)y.y; t[6]=(__bf16)y.z; t[7]=(__bf16)y.w;
                *(bf16x8*)(alw + j * 16) = t;
            }
        }
        __syncthreads();
        #pragma unroll
        for (int ks = 0; ks < 2; ++ks) {
            bf16x8 afr[4], bfr[4];
            #pragma unroll
            for (int mi = 0; mi < 4; ++mi) {
                int r = wm * 64 + mi * 16 + (lane & 15);
                afr[mi] = *(const bf16x8*)((const char*)Al + r * 144 + ks * 64 + (lane >> 4) * 16);
            }
            #pragma unroll
            for (int ni = 0; ni < 4; ++ni) {
                int r  = wn * 64 + ni * 16 + (lane & 15);
                int cb = (ks * 64 + (lane >> 4) * 16) ^ ((r & 7) << 4);
                bfr[ni] = *(const bf16x8*)((const char*)Bl + r * 128 + cb);
            }
            #pragma unroll
            for (int mi = 0; mi < 4; ++mi)
                #pragma unroll
                for (int ni = 0; ni < 4; ++ni)
                    acc[mi][ni] = __builtin_amdgcn_mfma_f32_16x16x32_bf16(
                        afr[mi], bfr[ni], acc[mi][ni], 0, 0, 0);
        }
        __syncthreads();
    }
    const int gm0 = bm + wm * 64;
    const int gn0 = bn + wn * 64 + (lane & 15);

    if (EPI == 0) {
        const int b = bm >> 13;
        const int h = (bn >> 6) + wn;
        float ksv[4];
        #pragma unroll
        for (int ni = 0; ni < 4; ++ni)
            ksv[ni] = aux[((b * 16 + h) << 6) + ni * 16 + (lane & 15)];
        #pragma unroll
        for (int mi = 0; mi < 4; ++mi) {
            #pragma unroll
            for (int j = 0; j < 4; ++j) {
                float pv[4], s = 0.0f;
                #pragma unroll
                for (int ni = 0; ni < 4; ++ni) {
                    pv[ni] = phi_f(acc[mi][ni][j]);
                    s += pv[ni] * ksv[ni];
                }
                s += __shfl_xor(s, 1);
                s += __shfl_xor(s, 2);
                s += __shfl_xor(s, 4);
                s += __shfl_xor(s, 8);
                float z = 1.0f / (s + 1e-6f);
                int gm = gm0 + mi * 16 + (lane >> 4) * 4 + j;
                __bf16* op = Out + (size_t)gm * H_ + gn0;
                #pragma unroll
                for (int ni = 0; ni < 4; ++ni)
                    op[ni * 16] = (__bf16)(pv[ni] * z);
            }
        }
    } else {
        #pragma unroll
        for (int mi = 0; mi < 4; ++mi) {
            #pragma unroll
            for (int j = 0; j < 4; ++j) {
                int gm = gm0 + mi * 16 + (lane >> 4) * 4 + j;
                float mv = mask[gm];
                __bf16* op = Out + (size_t)gm * H_ + gn0;
                #pragma unroll
                for (int ni = 0; ni < 4; ++ni) {
                    float v = acc[mi][ni][j];
                    if (EPI == 1) v = phi_f(v) * mv;
                    else          v = v * mv;
                    op[ni * 16] = (__bf16)v;
                }
            }
        }
    }
}

// ---------------------------------------------------------------------------
// Final GEMM (bf16 A = Q', bf16 W = per-batch U): out fp32.
// ---------------------------------------------------------------------------
__global__ __launch_bounds__(256, 2)
void gemm_fin(const __bf16* __restrict__ A, const __bf16* __restrict__ Wb,
              float* __restrict__ Out)
{
    const int orig = blockIdx.x;
    const int wgid = (orig & 7) * 256 + (orig >> 3);
    const int bm = (wgid >> 3) * 128;
    const int bn = (wgid & 7) * 128;
    const int tid  = threadIdx.x;
    const int lane = tid & 63;
    const int wid  = tid >> 6;
    const int wm = wid >> 1, wn = wid & 1;

    const __bf16* Wp = Wb + ((size_t)(bm >> 13) << 20);   // per-batch U

    __shared__ __bf16 Al[128 * 64];
    __shared__ __bf16 Bl[128 * 64];

    f32x4 acc[4][4];
    #pragma unroll
    for (int i = 0; i < 4; ++i)
        #pragma unroll
        for (int j = 0; j < 4; ++j) acc[i][j] = (f32x4)0.0f;

    const int sn = wid * 8 + (lane >> 3);
    const int sc = (lane & 7) * 16;

    for (int k0 = 0; k0 < H_; k0 += 64) {
        #pragma unroll
        for (int issue = 0; issue < 4; ++issue) {
            int n = issue * 32 + sn;
            int csw = sc ^ ((n & 7) << 4);
            async_copy16((const char*)(A  + (size_t)(bm + n) * H_ + k0) + csw,
                         (char*)Al + issue * 4096 + wid * 1024);
            async_copy16((const char*)(Wp + (size_t)(bn + n) * H_ + k0) + csw,
                         (char*)Bl + issue * 4096 + wid * 1024);
        }
        __syncthreads();
        #pragma unroll
        for (int ks = 0; ks < 2; ++ks) {
            bf16x8 afr[4], bfr[4];
            #pragma unroll
            for (int mi = 0; mi < 4; ++mi) {
                int r  = wm * 64 + mi * 16 + (lane & 15);
                int cb = (ks * 64 + (lane >> 4) * 16) ^ ((r & 7) << 4);
                afr[mi] = *(const bf16x8*)((const char*)Al + r * 128 + cb);
            }
            #pragma unroll
            for (int ni = 0; ni < 4; ++ni) {
                int r  = wn * 64 + ni * 16 + (lane & 15);
                int cb = (ks * 64 + (lane >> 4) * 16) ^ ((r & 7) << 4);
                bfr[ni] = *(const bf16x8*)((const char*)Bl + r * 128 + cb);
            }
            #pragma unroll
            for (int mi = 0; mi < 4; ++mi)
                #pragma unroll
                for (int ni = 0; ni < 4; ++ni)
                    acc[mi][ni] = __builtin_amdgcn_mfma_f32_16x16x32_bf16(
                        afr[mi], bfr[ni], acc[mi][ni], 0, 0, 0);
        }
        __syncthreads();
    }
    const int gm0 = bm + wm * 64;
    const int gn0 = bn + wn * 64 + (lane & 15);
    #pragma unroll
    for (int mi = 0; mi < 4; ++mi)
        #pragma unroll
        for (int j = 0; j < 4; ++j) {
            int gm = gm0 + mi * 16 + (lane >> 4) * 4 + j;
            float* op = Out + (size_t)gm * H_ + gn0;
            #pragma unroll
            for (int ni = 0; ni < 4; ++ni)
                op[ni * 16] = acc[mi][ni][j];
        }
}

// ---------------------------------------------------------------------------
// KV partials via MFMA (unchanged, passing)
// ---------------------------------------------------------------------------
__global__ __launch_bounds__(256, 2)
void kv_kernel(const __bf16* __restrict__ Kb, const __bf16* __restrict__ Vb,
               float* __restrict__ KVp, float* __restrict__ Ksp)
{
    const int chunk = blockIdx.x;
    const int bh = blockIdx.y;
    const int b = bh >> 4, h = bh & 15;
    const int tid = threadIdx.x, lane = tid & 63, wid = tid >> 6;

    __shared__ char KtRaw[64 * 144];
    __shared__ char VtRaw[64 * 144];
    __shared__ float ksbuf[32][64];

    const int st  = tid >> 3;
    const int dkg = tid & 7;
    const int dk0 = dkg * 8;
    const int swzT = (dkg & 7) << 4;

    f32x4 acc[4];
    #pragma unroll
    for (int i = 0; i < 4; ++i) acc[i] = (f32x4)0.0f;
    float ksacc[8];
    #pragma unroll
    for (int i = 0; i < 8; ++i) ksacc[i] = 0.0f;

    const size_t gbase = ((size_t)b * T_ + (size_t)chunk * 1024) * H_
                         + h * 64 + dk0;

    bf16x8 ka, kc, va, vc;
    {
        const __bf16* p  = Kb + gbase;
        const __bf16* pv = Vb + gbase;
        ka = *(const bf16x8*)(p  + (size_t)st * H_);
        kc = *(const bf16x8*)(p  + (size_t)(st + 32) * H_);
        va = *(const bf16x8*)(pv + (size_t)st * H_);
        vc = *(const bf16x8*)(pv + (size_t)(st + 32) * H_);
    }

    for (int tile = 0; tile < 16; ++tile) {
        __syncthreads();
        #pragma unroll
        for (int j = 0; j < 8; ++j) {
            int rowb = (dk0 + j) * 144;
            *(__bf16*)(KtRaw + ((rowb + 2*st)        ^ swzT)) = ka[j];
            *(__bf16*)(KtRaw + ((rowb + 2*(st + 32)) ^ swzT)) = kc[j];
            *(__bf16*)(VtRaw + ((rowb + 2*st)        ^ swzT)) = va[j];
            *(__bf16*)(VtRaw + ((rowb + 2*(st + 32)) ^ swzT)) = vc[j];
            ksacc[j] += (float)ka[j] + (float)kc[j];
        }
        if (tile < 15) {
            const __bf16* p  = Kb + gbase + (size_t)(tile + 1) * 64 * H_;
            const __bf16* pv = Vb + gbase + (size_t)(tile + 1) * 64 * H_;
            ka = *(const bf16x8*)(p  + (size_t)st * H_);
            kc = *(const bf16x8*)(p  + (size_t)(st + 32) * H_);
            va = *(const bf16x8*)(pv + (size_t)st * H_);
            vc = *(const bf16x8*)(pv + (size_t)(st + 32) * H_);
        }
        __syncthreads();
        #pragma unroll
        for (int ks = 0; ks < 2; ++ks) {
            int r = wid * 16 + (lane & 15);
            int cb = (r * 144 + (ks * 64 + (lane >> 4) * 16)) ^ (((r >> 3) & 7) << 4);
            bf16x8 af = *(const bf16x8*)(KtRaw + cb);
            #pragma unroll
            for (int ni = 0; ni < 4; ++ni) {
                int rv = ni * 16 + (lane & 15);
                int cv = (rv * 144 + (ks * 64 + (lane >> 4) * 16)) ^ (((rv >> 3) & 7) << 4);
                bf16x8 bf = *(const bf16x8*)(VtRaw + cv);
                acc[ni] = __builtin_amdgcn_mfma_f32_16x16x32_bf16(af, bf, acc[ni], 0, 0, 0);
            }
        }
    }

    float* kvp = KVp + ((size_t)chunk * 64 + bh) * 4096;
    #pragma unroll
    for (int ni = 0; ni < 4; ++ni)
        #pragma unroll
        for (int jj = 0; jj < 4; ++jj) {
            int dk = wid * 16 + (lane >> 4) * 4 + jj;
            int dv = ni * 16 + (lane & 15);
            kvp[dk * 64 + dv] = acc[ni][jj];
        }

    #pragma unroll
    for (int j = 0; j < 8; ++j)
        ksbuf[st][dk0 + j] = ksacc[j];
    __syncthreads();
    if (tid < 64) {
        float s = 0.0f;
        #pragma unroll 8
        for (int st2 = 0; st2 < 32; ++st2) s += ksbuf[st2][tid];
        Ksp[((size_t)chunk * 64 + bh) * 64 + tid] = s;
    }
}

// sum 8 chunk-partials -> KVb bf16 [bh][dk][dv] + Ks fp32 [bh][dk]
__global__ void kvsum(const float* __restrict__ KVp, const float* __restrict__ Ksp,
                      __bf16* __restrict__ KVb, float* __restrict__ Ks) {
    int bh = blockIdx.x, tid = threadIdx.x;
    __bf16* d = KVb + (size_t)bh * 4096;
    for (int i = tid; i < 4096; i += 256) {
        float s = 0.0f;
        #pragma unroll
        for (int c = 0; c < 8; ++c)
            s += KVp[((size_t)c * 64 + bh) * 4096 + i];
        d[i] = (__bf16)s;
    }
    if (tid < 64) {
        float s = 0.0f;
        #pragma unroll
        for (int c = 0; c < 8; ++c)
            s += Ksp[((size_t)c * 64 + bh) * 64 + tid];
        Ks[bh * 64 + tid] = s;
    }
}

// ---------------------------------------------------------------------------
// Ut[b][m][h*64+dk] = sum_dv Wob[m][h*64+dv] * KVb[b*16+h][dk][dv]
// ---------------------------------------------------------------------------
__global__ __launch_bounds__(256)
void ugemm(const __bf16* __restrict__ Wob, const __bf16* __restrict__ KVb,
           __bf16* __restrict__ Ut)
{
    const int mp = blockIdx.x, bhp = blockIdx.y;
    const int b = bhp >> 3, hp = bhp & 7;
    const int tid = threadIdx.x, lane = tid & 63, w = tid >> 6;
    const int wm = w >> 1, wn = w & 1;
    const int h = hp * 2 + wn;
    const int bm = mp * 128;
    const int lane15 = lane & 15;

    __shared__ __bf16 As[128][136];
    __shared__ __bf16 Bs[2][64][72];

    {
        int r = tid >> 1, c0 = (tid & 1) * 64;
        const __bf16* src = Wob + (size_t)(bm + r) * H_ + hp * 128 + c0;
        #pragma unroll
        for (int j = 0; j < 8; ++j)
            *(bf16x8*)&As[r][c0 + j*8] = *(const bf16x8*)(src + j*8);
    }
    {
        int hh = tid >> 7, idx = tid & 127, r = idx >> 1, c0 = (idx & 1) * 32;
        const __bf16* src = KVb + ((size_t)(b * 16 + hp * 2 + hh) * 64 + r) * 64 + c0;
        #pragma unroll
        for (int j = 0; j < 4; ++j)
            *(bf16x8*)&Bs[hh][r][c0 + j*8] = *(const bf16x8*)(src + j*8);
    }
    __syncthreads();

    f32x4 acc[4][4];
    #pragma unroll
    for (int i = 0; i < 4; ++i)
        #pragma unroll
        for (int j = 0; j < 4; ++j) acc[i][j] = (f32x4)0.0f;

    #pragma unroll
    for (int ks = 0; ks < 2; ++ks) {
        bf16x8 afr[4], bfr[4];
        #pragma unroll
        for (int mi = 0; mi < 4; ++mi)
            afr[mi] = *(const bf16x8*)&As[wm*64 + mi*16 + lane15]
                                         [wn*64 + ks*32 + (lane>>4)*8];
        #pragma unroll
        for (int ni = 0; ni < 4; ++ni)
            bfr[ni] = *(const bf16x8*)&Bs[wn][ni*16 + lane15]
                                         [ks*32 + (lane>>4)*8];
        #pragma unroll
        for (int mi = 0; mi < 4; ++mi)
            #pragma unroll
            for (int ni = 0; ni < 4; ++ni)
                acc[mi][ni] = __builtin_amdgcn_mfma_f32_16x16x32_bf16(
                    afr[mi], bfr[ni], acc[mi][ni], 0, 0, 0);
    }

    __bf16* up = Ut + ((size_t)b << 20);
    #pragma unroll
    for (int mi = 0; mi < 4; ++mi)
        #pragma unroll
        for (int j = 0; j < 4; ++j) {
            int m2 = bm + wm * 64 + mi * 16 + (lane >> 4) * 4 + j;
            #pragma unroll
            for (int ni = 0; ni < 4; ++ni) {
                int dk = ni * 16 + lane15;
                up[(size_t)m2 * H_ + h * 64 + dk] = (__bf16)acc[mi][ni][j];
            }
        }
}

// ---------------------------------------------------------------------------
extern "C" void kernel_launch(void* const* d_in, const int* in_sizes, int n_in,
                              void* d_out, int out_size, void* d_ws, size_t ws_size,
                              hipStream_t stream) {
    (void)in_sizes; (void)n_in; (void)out_size; (void)ws_size;
    const float* q    = (const float*)d_in[0];
    const float* k    = (const float*)d_in[1];
    const float* v    = (const float*)d_in[2];
    const float* mask = (const float*)d_in[3];
    const float* Wq   = (const float*)d_in[4];
    const float* Wk   = (const float*)d_in[5];
    const float* Wv   = (const float*)d_in[6];
    const float* Wo   = (const float*)d_in[7];
    float* out = (float*)d_out;

    char* ws = (char*)d_ws;
    const size_t WELEM = (size_t)H_ * H_;
    const size_t PELEM = (size_t)BT_ * H_;
    __bf16* Wqb = (__bf16*)ws;
    __bf16* Wkb = Wqb + WELEM;
    __bf16* Wvb = Wkb + WELEM;
    __bf16* Wob = Wvb + WELEM;
    __bf16* Qb  = Wob + WELEM;                 // Q' buffer
    __bf16* Kb  = Qb + PELEM;
    __bf16* Vb  = Kb + PELEM;
    float*  KVp = (float*)(Vb + PELEM);        // 8 MiB partials; reused as Ut
    float*  Ksp = KVp + (size_t)8 * 64 * 4096;
    float*  Ksf = Ksp + (size_t)8 * 64 * 64;
    __bf16* KVb = (__bf16*)(Ksf + (size_t)64 * 64);
    __bf16* Ut  = (__bf16*)KVp;                // aliases dead KVp (8 MiB)

    wconv4<<<dim3(1024, 4), 256, 0, stream>>>(Wq, Wk, Wv, Wo, Wqb, Wkb, Wvb, Wob);

    gemm_f32a<1><<<2048, 256, 0, stream>>>(k, Wkb, mask, nullptr, Kb);
    gemm_f32a<2><<<2048, 256, 0, stream>>>(v, Wvb, mask, nullptr, Vb);

    kv_kernel<<<dim3(T_/1024, B_*NH_), 256, 0, stream>>>(Kb, Vb, KVp, Ksp);
    kvsum<<<B_*NH_, 256, 0, stream>>>(KVp, Ksp, KVb, Ksf);
    ugemm<<<dim3(8, 32), 256, 0, stream>>>(Wob, KVb, Ut);

    gemm_f32a<0><<<2048, 256, 0, stream>>>(q, Wqb, mask, Ksf, Qb);
    gemm_fin<<<2048, 256, 0, stream>>>(Qb, Ut, out);
}

// Round 10
// 453.609 us; speedup vs baseline: 1.3893x; 1.3893x over previous
//
#include <hip/hip_runtime.h>
#include <hip/hip_bf16.h>
#include <stdint.h>

#define B_  4
#define T_  8192
#define H_  1024
#define NH_ 16
#define D_  64
#define BT_ (B_*T_)

typedef __attribute__((ext_vector_type(8))) __bf16 bf16x8;
typedef __attribute__((ext_vector_type(4))) __bf16 bf16x4;
typedef __attribute__((ext_vector_type(4))) float  f32x4;

__device__ __forceinline__ float phi_f(float x) {
    return x > 0.0f ? x + 1.0f : __expf(x);
}

__device__ __forceinline__ void async_copy16(const void* g, void* l) {
    __builtin_amdgcn_global_load_lds(
        (const __attribute__((address_space(1))) uint32_t*)g,
        (__attribute__((address_space(3))) uint32_t*)l, 16, 0, 0);
}

__global__ void wconv4(const float* __restrict__ s0, const float* __restrict__ s1,
                       const float* __restrict__ s2, const float* __restrict__ s3,
                       __bf16* __restrict__ d0, __bf16* __restrict__ d1,
                       __bf16* __restrict__ d2, __bf16* __restrict__ d3) {
    const float* s; __bf16* d;
    switch (blockIdx.y) {
        case 0: s = s0; d = d0; break;
        case 1: s = s1; d = d1; break;
        case 2: s = s2; d = d2; break;
        default: s = s3; d = d3; break;
    }
    int i = (blockIdx.x * 256 + threadIdx.x) * 4;
    float4 v = *(const float4*)(s + i);
    bf16x4 o;
    o[0] = (__bf16)v.x; o[1] = (__bf16)v.y; o[2] = (__bf16)v.z; o[3] = (__bf16)v.w;
    *(bf16x4*)(d + i) = o;
}

// ---------------------------------------------------------------------------
// Projection GEMM, fp32 A staged DIRECTLY via global_load_lds (async, no VGPR
// round-trip): Al = f32 [128][64], 256B rows, XOR swizzle seg^=(row&15);
// source pre-swizzled so linear dest + swizzled read is an involution.
// fp32->bf16 conversion happens at frag-read time (2x ds_read_b128 + cvt).
// B bf16 via the verified gload_lds + ((n&7)<<4) swizzle.
// EPI: 0 = Q' = z*phi -> bf16 (aux = Ksum), 1 = phi*mask -> bf16 (K),
//      2 = mask -> bf16 (V)
// ---------------------------------------------------------------------------
template<int EPI>
__global__ __launch_bounds__(256, 2)
void gemm_f32a(const float* __restrict__ A, const __bf16* __restrict__ Wb,
               const float* __restrict__ mask, const float* __restrict__ aux,
               __bf16* __restrict__ Out)
{
    const int orig = blockIdx.x;
    const int wgid = (orig & 7) * 256 + (orig >> 3);   // nwg=2048, bijective
    const int bm = (wgid >> 3) * 128;
    const int bn = (wgid & 7) * 128;
    const int tid  = threadIdx.x;
    const int lane = tid & 63;
    const int wid  = tid >> 6;
    const int wm = wid >> 1, wn = wid & 1;

    __shared__ __align__(16) char Al[32768];   // f32 [128][64], swizzled
    __shared__ __align__(16) char Bl[16384];   // bf16 [128][64], swizzled

    f32x4 acc[4][4];
    #pragma unroll
    for (int i = 0; i < 4; ++i)
        #pragma unroll
        for (int j = 0; j < 4; ++j) acc[i][j] = (f32x4)0.0f;

    // A staging: 8 issues; issue i covers row i*16 + (tid>>4), seg tid&15.
    const int arow = tid >> 4;
    const int acsw = ((tid & 15) << 4) ^ ((arow & 15) << 4);  // src in-row byte
    // B staging
    const int sn = wid * 8 + (lane >> 3);
    const int sc = (lane & 7) * 16;

    for (int k0 = 0; k0 < H_; k0 += 64) {
        #pragma unroll
        for (int i = 0; i < 8; ++i) {
            const char* src = (const char*)(A + (size_t)(bm + i * 16 + arow) * H_ + k0) + acsw;
            async_copy16(src, (char*)Al + i * 4096 + wid * 1024);
        }
        #pragma unroll
        for (int issue = 0; issue < 4; ++issue) {
            int n = issue * 32 + sn;
            int csw = sc ^ ((n & 7) << 4);
            async_copy16((const char*)(Wb + (size_t)(bn + n) * H_ + k0) + csw,
                         (char*)Bl + issue * 4096 + wid * 1024);
        }
        __syncthreads();   // drains all global_load_lds
        #pragma unroll
        for (int ks = 0; ks < 2; ++ks) {
            bf16x8 afr[4], bfr[4];
            const int q = lane >> 4;
            #pragma unroll
            for (int mi = 0; mi < 4; ++mi) {
                int r = wm * 64 + mi * 16 + (lane & 15);
                int seg0 = ks * 8 + q * 2;
                int rs = (r & 15) << 4;
                f32x4 lo = *(const f32x4*)(Al + r * 256 + (((seg0    ) << 4) ^ rs));
                f32x4 hi = *(const f32x4*)(Al + r * 256 + (((seg0 + 1) << 4) ^ rs));
                bf16x8 t;
                t[0]=(__bf16)lo[0]; t[1]=(__bf16)lo[1]; t[2]=(__bf16)lo[2]; t[3]=(__bf16)lo[3];
                t[4]=(__bf16)hi[0]; t[5]=(__bf16)hi[1]; t[6]=(__bf16)hi[2]; t[7]=(__bf16)hi[3];
                afr[mi] = t;
            }
            #pragma unroll
            for (int ni = 0; ni < 4; ++ni) {
                int r  = wn * 64 + ni * 16 + (lane & 15);
                int cb = (ks * 64 + q * 16) ^ ((r & 7) << 4);
                bfr[ni] = *(const bf16x8*)(Bl + r * 128 + cb);
            }
            #pragma unroll
            for (int mi = 0; mi < 4; ++mi)
                #pragma unroll
                for (int ni = 0; ni < 4; ++ni)
                    acc[mi][ni] = __builtin_amdgcn_mfma_f32_16x16x32_bf16(
                        afr[mi], bfr[ni], acc[mi][ni], 0, 0, 0);
        }
        __syncthreads();
    }
    const int gm0 = bm + wm * 64;
    const int gn0 = bn + wn * 64 + (lane & 15);

    if (EPI == 0) {
        const int b = bm >> 13;
        const int h = (bn >> 6) + wn;
        float ksv[4];
        #pragma unroll
        for (int ni = 0; ni < 4; ++ni)
            ksv[ni] = aux[((b * 16 + h) << 6) + ni * 16 + (lane & 15)];
        #pragma unroll
        for (int mi = 0; mi < 4; ++mi) {
            #pragma unroll
            for (int j = 0; j < 4; ++j) {
                float pv[4], s = 0.0f;
                #pragma unroll
                for (int ni = 0; ni < 4; ++ni) {
                    pv[ni] = phi_f(acc[mi][ni][j]);
                    s += pv[ni] * ksv[ni];
                }
                s += __shfl_xor(s, 1);
                s += __shfl_xor(s, 2);
                s += __shfl_xor(s, 4);
                s += __shfl_xor(s, 8);
                float z = 1.0f / (s + 1e-6f);
                int gm = gm0 + mi * 16 + (lane >> 4) * 4 + j;
                __bf16* op = Out + (size_t)gm * H_ + gn0;
                #pragma unroll
                for (int ni = 0; ni < 4; ++ni)
                    op[ni * 16] = (__bf16)(pv[ni] * z);
            }
        }
    } else {
        #pragma unroll
        for (int mi = 0; mi < 4; ++mi) {
            #pragma unroll
            for (int j = 0; j < 4; ++j) {
                int gm = gm0 + mi * 16 + (lane >> 4) * 4 + j;
                float mv = mask[gm];
                __bf16* op = Out + (size_t)gm * H_ + gn0;
                #pragma unroll
                for (int ni = 0; ni < 4; ++ni) {
                    float v = acc[mi][ni][j];
                    if (EPI == 1) v = phi_f(v) * mv;
                    else          v = v * mv;
                    op[ni * 16] = (__bf16)v;
                }
            }
        }
    }
}

// ---------------------------------------------------------------------------
// Final GEMM (bf16 A = Q', bf16 W = per-batch U): out fp32.
// ---------------------------------------------------------------------------
__global__ __launch_bounds__(256, 2)
void gemm_fin(const __bf16* __restrict__ A, const __bf16* __restrict__ Wb,
              float* __restrict__ Out)
{
    const int orig = blockIdx.x;
    const int wgid = (orig & 7) * 256 + (orig >> 3);
    const int bm = (wgid >> 3) * 128;
    const int bn = (wgid & 7) * 128;
    const int tid  = threadIdx.x;
    const int lane = tid & 63;
    const int wid  = tid >> 6;
    const int wm = wid >> 1, wn = wid & 1;

    const __bf16* Wp = Wb + ((size_t)(bm >> 13) << 20);   // per-batch U

    __shared__ __bf16 Al[128 * 64];
    __shared__ __bf16 Bl[128 * 64];

    f32x4 acc[4][4];
    #pragma unroll
    for (int i = 0; i < 4; ++i)
        #pragma unroll
        for (int j = 0; j < 4; ++j) acc[i][j] = (f32x4)0.0f;

    const int sn = wid * 8 + (lane >> 3);
    const int sc = (lane & 7) * 16;

    for (int k0 = 0; k0 < H_; k0 += 64) {
        #pragma unroll
        for (int issue = 0; issue < 4; ++issue) {
            int n = issue * 32 + sn;
            int csw = sc ^ ((n & 7) << 4);
            async_copy16((const char*)(A  + (size_t)(bm + n) * H_ + k0) + csw,
                         (char*)Al + issue * 4096 + wid * 1024);
            async_copy16((const char*)(Wp + (size_t)(bn + n) * H_ + k0) + csw,
                         (char*)Bl + issue * 4096 + wid * 1024);
        }
        __syncthreads();
        #pragma unroll
        for (int ks = 0; ks < 2; ++ks) {
            bf16x8 afr[4], bfr[4];
            #pragma unroll
            for (int mi = 0; mi < 4; ++mi) {
                int r  = wm * 64 + mi * 16 + (lane & 15);
                int cb = (ks * 64 + (lane >> 4) * 16) ^ ((r & 7) << 4);
                afr[mi] = *(const bf16x8*)((const char*)Al + r * 128 + cb);
            }
            #pragma unroll
            for (int ni = 0; ni < 4; ++ni) {
                int r  = wn * 64 + ni * 16 + (lane & 15);
                int cb = (ks * 64 + (lane >> 4) * 16) ^ ((r & 7) << 4);
                bfr[ni] = *(const bf16x8*)((const char*)Bl + r * 128 + cb);
            }
            #pragma unroll
            for (int mi = 0; mi < 4; ++mi)
                #pragma unroll
                for (int ni = 0; ni < 4; ++ni)
                    acc[mi][ni] = __builtin_amdgcn_mfma_f32_16x16x32_bf16(
                        afr[mi], bfr[ni], acc[mi][ni], 0, 0, 0);
        }
        __syncthreads();
    }
    const int gm0 = bm + wm * 64;
    const int gn0 = bn + wn * 64 + (lane & 15);
    #pragma unroll
    for (int mi = 0; mi < 4; ++mi)
        #pragma unroll
        for (int j = 0; j < 4; ++j) {
            int gm = gm0 + mi * 16 + (lane >> 4) * 4 + j;
            float* op = Out + (size_t)gm * H_ + gn0;
            #pragma unroll
            for (int ni = 0; ni < 4; ++ni)
                op[ni * 16] = acc[mi][ni][j];
        }
}

// ---------------------------------------------------------------------------
// KV partials via MFMA (unchanged, passing)
// ---------------------------------------------------------------------------
__global__ __launch_bounds__(256, 2)
void kv_kernel(const __bf16* __restrict__ Kb, const __bf16* __restrict__ Vb,
               float* __restrict__ KVp, float* __restrict__ Ksp)
{
    const int chunk = blockIdx.x;
    const int bh = blockIdx.y;
    const int b = bh >> 4, h = bh & 15;
    const int tid = threadIdx.x, lane = tid & 63, wid = tid >> 6;

    __shared__ char KtRaw[64 * 144];
    __shared__ char VtRaw[64 * 144];
    __shared__ float ksbuf[32][64];

    const int st  = tid >> 3;
    const int dkg = tid & 7;
    const int dk0 = dkg * 8;
    const int swzT = (dkg & 7) << 4;

    f32x4 acc[4];
    #pragma unroll
    for (int i = 0; i < 4; ++i) acc[i] = (f32x4)0.0f;
    float ksacc[8];
    #pragma unroll
    for (int i = 0; i < 8; ++i) ksacc[i] = 0.0f;

    const size_t gbase = ((size_t)b * T_ + (size_t)chunk * 1024) * H_
                         + h * 64 + dk0;

    bf16x8 ka, kc, va, vc;
    {
        const __bf16* p  = Kb + gbase;
        const __bf16* pv = Vb + gbase;
        ka = *(const bf16x8*)(p  + (size_t)st * H_);
        kc = *(const bf16x8*)(p  + (size_t)(st + 32) * H_);
        va = *(const bf16x8*)(pv + (size_t)st * H_);
        vc = *(const bf16x8*)(pv + (size_t)(st + 32) * H_);
    }

    for (int tile = 0; tile < 16; ++tile) {
        __syncthreads();
        #pragma unroll
        for (int j = 0; j < 8; ++j) {
            int rowb = (dk0 + j) * 144;
            *(__bf16*)(KtRaw + ((rowb + 2*st)        ^ swzT)) = ka[j];
            *(__bf16*)(KtRaw + ((rowb + 2*(st + 32)) ^ swzT)) = kc[j];
            *(__bf16*)(VtRaw + ((rowb + 2*st)        ^ swzT)) = va[j];
            *(__bf16*)(VtRaw + ((rowb + 2*(st + 32)) ^ swzT)) = vc[j];
            ksacc[j] += (float)ka[j] + (float)kc[j];
        }
        if (tile < 15) {
            const __bf16* p  = Kb + gbase + (size_t)(tile + 1) * 64 * H_;
            const __bf16* pv = Vb + gbase + (size_t)(tile + 1) * 64 * H_;
            ka = *(const bf16x8*)(p  + (size_t)st * H_);
            kc = *(const bf16x8*)(p  + (size_t)(st + 32) * H_);
            va = *(const bf16x8*)(pv + (size_t)st * H_);
            vc = *(const bf16x8*)(pv + (size_t)(st + 32) * H_);
        }
        __syncthreads();
        #pragma unroll
        for (int ks = 0; ks < 2; ++ks) {
            int r = wid * 16 + (lane & 15);
            int cb = (r * 144 + (ks * 64 + (lane >> 4) * 16)) ^ (((r >> 3) & 7) << 4);
            bf16x8 af = *(const bf16x8*)(KtRaw + cb);
            #pragma unroll
            for (int ni = 0; ni < 4; ++ni) {
                int rv = ni * 16 + (lane & 15);
                int cv = (rv * 144 + (ks * 64 + (lane >> 4) * 16)) ^ (((rv >> 3) & 7) << 4);
                bf16x8 bf = *(const bf16x8*)(VtRaw + cv);
                acc[ni] = __builtin_amdgcn_mfma_f32_16x16x32_bf16(af, bf, acc[ni], 0, 0, 0);
            }
        }
    }

    float* kvp = KVp + ((size_t)chunk * 64 + bh) * 4096;
    #pragma unroll
    for (int ni = 0; ni < 4; ++ni)
        #pragma unroll
        for (int jj = 0; jj < 4; ++jj) {
            int dk = wid * 16 + (lane >> 4) * 4 + jj;
            int dv = ni * 16 + (lane & 15);
            kvp[dk * 64 + dv] = acc[ni][jj];
        }

    #pragma unroll
    for (int j = 0; j < 8; ++j)
        ksbuf[st][dk0 + j] = ksacc[j];
    __syncthreads();
    if (tid < 64) {
        float s = 0.0f;
        #pragma unroll 8
        for (int st2 = 0; st2 < 32; ++st2) s += ksbuf[st2][tid];
        Ksp[((size_t)chunk * 64 + bh) * 64 + tid] = s;
    }
}

// sum 8 chunk-partials -> KVb bf16 [bh][dk][dv] + Ks fp32 [bh][dk]
__global__ void kvsum(const float* __restrict__ KVp, const float* __restrict__ Ksp,
                      __bf16* __restrict__ KVb, float* __restrict__ Ks) {
    int bh = blockIdx.x, tid = threadIdx.x;
    __bf16* d = KVb + (size_t)bh * 4096;
    for (int i = tid; i < 4096; i += 256) {
        float s = 0.0f;
        #pragma unroll
        for (int c = 0; c < 8; ++c)
            s += KVp[((size_t)c * 64 + bh) * 4096 + i];
        d[i] = (__bf16)s;
    }
    if (tid < 64) {
        float s = 0.0f;
        #pragma unroll
        for (int c = 0; c < 8; ++c)
            s += Ksp[((size_t)c * 64 + bh) * 64 + tid];
        Ks[bh * 64 + tid] = s;
    }
}

// ---------------------------------------------------------------------------
// Ut[b][m][h*64+dk] = sum_dv Wob[m][h*64+dv] * KVb[b*16+h][dk][dv]
// ---------------------------------------------------------------------------
__global__ __launch_bounds__(256)
void ugemm(const __bf16* __restrict__ Wob, const __bf16* __restrict__ KVb,
           __bf16* __restrict__ Ut)
{
    const int mp = blockIdx.x, bhp = blockIdx.y;
    const int b = bhp >> 3, hp = bhp & 7;
    const int tid = threadIdx.x, lane = tid & 63, w = tid >> 6;
    const int wm = w >> 1, wn = w & 1;
    const int h = hp * 2 + wn;
    const int bm = mp * 128;
    const int lane15 = lane & 15;

    __shared__ __bf16 As[128][136];
    __shared__ __bf16 Bs[2][64][72];

    {
        int r = tid >> 1, c0 = (tid & 1) * 64;
        const __bf16* src = Wob + (size_t)(bm + r) * H_ + hp * 128 + c0;
        #pragma unroll
        for (int j = 0; j < 8; ++j)
            *(bf16x8*)&As[r][c0 + j*8] = *(const bf16x8*)(src + j*8);
    }
    {
        int hh = tid >> 7, idx = tid & 127, r = idx >> 1, c0 = (idx & 1) * 32;
        const __bf16* src = KVb + ((size_t)(b * 16 + hp * 2 + hh) * 64 + r) * 64 + c0;
        #pragma unroll
        for (int j = 0; j < 4; ++j)
            *(bf16x8*)&Bs[hh][r][c0 + j*8] = *(const bf16x8*)(src + j*8);
    }
    __syncthreads();

    f32x4 acc[4][4];
    #pragma unroll
    for (int i = 0; i < 4; ++i)
        #pragma unroll
        for (int j = 0; j < 4; ++j) acc[i][j] = (f32x4)0.0f;

    #pragma unroll
    for (int ks = 0; ks < 2; ++ks) {
        bf16x8 afr[4], bfr[4];
        #pragma unroll
        for (int mi = 0; mi < 4; ++mi)
            afr[mi] = *(const bf16x8*)&As[wm*64 + mi*16 + lane15]
                                         [wn*64 + ks*32 + (lane>>4)*8];
        #pragma unroll
        for (int ni = 0; ni < 4; ++ni)
            bfr[ni] = *(const bf16x8*)&Bs[wn][ni*16 + lane15]
                                         [ks*32 + (lane>>4)*8];
        #pragma unroll
        for (int mi = 0; mi < 4; ++mi)
            #pragma unroll
            for (int ni = 0; ni < 4; ++ni)
                acc[mi][ni] = __builtin_amdgcn_mfma_f32_16x16x32_bf16(
                    afr[mi], bfr[ni], acc[mi][ni], 0, 0, 0);
    }

    __bf16* up = Ut + ((size_t)b << 20);
    #pragma unroll
    for (int mi = 0; mi < 4; ++mi)
        #pragma unroll
        for (int j = 0; j < 4; ++j) {
            int m2 = bm + wm * 64 + mi * 16 + (lane >> 4) * 4 + j;
            #pragma unroll
            for (int ni = 0; ni < 4; ++ni) {
                int dk = ni * 16 + lane15;
                up[(size_t)m2 * H_ + h * 64 + dk] = (__bf16)acc[mi][ni][j];
            }
        }
}

// ---------------------------------------------------------------------------
extern "C" void kernel_launch(void* const* d_in, const int* in_sizes, int n_in,
                              void* d_out, int out_size, void* d_ws, size_t ws_size,
                              hipStream_t stream) {
    (void)in_sizes; (void)n_in; (void)out_size; (void)ws_size;
    const float* q    = (const float*)d_in[0];
    const float* k    = (const float*)d_in[1];
    const float* v    = (const float*)d_in[2];
    const float* mask = (const float*)d_in[3];
    const float* Wq   = (const float*)d_in[4];
    const float* Wk   = (const float*)d_in[5];
    const float* Wv   = (const float*)d_in[6];
    const float* Wo   = (const float*)d_in[7];
    float* out = (float*)d_out;

    char* ws = (char*)d_ws;
    const size_t WELEM = (size_t)H_ * H_;
    const size_t PELEM = (size_t)BT_ * H_;
    __bf16* Wqb = (__bf16*)ws;
    __bf16* Wkb = Wqb + WELEM;
    __bf16* Wvb = Wkb + WELEM;
    __bf16* Wob = Wvb + WELEM;
    __bf16* Qb  = Wob + WELEM;                 // Q' buffer
    __bf16* Kb  = Qb + PELEM;
    __bf16* Vb  = Kb + PELEM;
    float*  KVp = (float*)(Vb + PELEM);        // 8 MiB partials; reused as Ut
    float*  Ksp = KVp + (size_t)8 * 64 * 4096;
    float*  Ksf = Ksp + (size_t)8 * 64 * 64;
    __bf16* KVb = (__bf16*)(Ksf + (size_t)64 * 64);
    __bf16* Ut  = (__bf16*)KVp;                // aliases dead KVp (8 MiB)

    wconv4<<<dim3(1024, 4), 256, 0, stream>>>(Wq, Wk, Wv, Wo, Wqb, Wkb, Wvb, Wob);

    gemm_f32a<1><<<2048, 256, 0, stream>>>(k, Wkb, mask, nullptr, Kb);
    gemm_f32a<2><<<2048, 256, 0, stream>>>(v, Wvb, mask, nullptr, Vb);

    kv_kernel<<<dim3(T_/1024, B_*NH_), 256, 0, stream>>>(Kb, Vb, KVp, Ksp);
    kvsum<<<B_*NH_, 256, 0, stream>>>(KVp, Ksp, KVb, Ksf);
    ugemm<<<dim3(8, 32), 256, 0, stream>>>(Wob, KVb, Ut);

    gemm_f32a<0><<<2048, 256, 0, stream>>>(q, Wqb, mask, Ksf, Qb);
    gemm_fin<<<2048, 256, 0, stream>>>(Qb, Ut, out);
}